// Round 1
// baseline (101.289 us; speedup 1.0000x reference)
//
#include <hip/hip_runtime.h>
#include <hip/hip_bf16.h>

#define B_ 2
#define H_ 16
#define S_ 2048
#define D_ 64
#define QBLK 64
#define KVB 64

typedef __attribute__((ext_vector_type(8))) short bf16x8;
typedef __attribute__((ext_vector_type(8))) unsigned short u16x8;
typedef __attribute__((ext_vector_type(4))) float f32x4;

// fp32 -> bf16 (round-to-nearest-even), bit-level (values are finite)
__device__ __forceinline__ unsigned short f2bf(float x) {
  unsigned int u = __builtin_bit_cast(unsigned int, x);
  unsigned int r = (u + 0x7FFFu + ((u >> 16) & 1u)) >> 16;
  return (unsigned short)r;
}

__launch_bounds__(256)
__global__ void attn_fwd(const float* __restrict__ Q, const float* __restrict__ K,
                         const float* __restrict__ V, float* __restrict__ O) {
  const int bh  = blockIdx.x;   // 0..31  (batch*head)
  const int qt  = blockIdx.y;   // 0..31  (q tile of 64 rows)
  const int tid = threadIdx.x;
  const int wave = tid >> 6;
  const int lane = tid & 63;
  const int col  = lane & 15;   // MFMA n/col index (and A row index)
  const int g    = lane >> 4;   // 4-lane-group id 0..3

  // K tile row-major [kv][d], XOR-swizzled in 16B chunks: chunk ^= (kv&7)
  __shared__ __align__(16) unsigned short Kl[KVB][64];
  // V tile transposed [d][kv], XOR-swizzled: chunk ^= (d&7)
  __shared__ __align__(16) unsigned short Vt[64][KVB];
  // per-wave P buffer [qrow 16][kv 64 (+8 pad)]
  __shared__ __align__(16) unsigned short Pl[4][16][72];

  const float SCALE = 0.18033688011112042f; // (1/8) * log2(e)

  const float* Qh = Q + (size_t)bh * S_ * D_;
  const float* Kh = K + (size_t)bh * S_ * D_;
  const float* Vh = V + (size_t)bh * S_ * D_;
  float*       Oh = O + (size_t)bh * S_ * D_;

  // ---- Q fragments (A operand): row = lane%16, k = 32*kk + 8*g + i ----
  const int qrow = qt * QBLK + wave * 16 + col;
  bf16x8 qf[2];
  for (int kk = 0; kk < 2; ++kk) {
    const float* p = Qh + qrow * D_ + kk * 32 + g * 8;
    float4 a = *(const float4*)p;
    float4 b = *(const float4*)(p + 4);
    float v[8] = {a.x, a.y, a.z, a.w, b.x, b.y, b.z, b.w};
    for (int i = 0; i < 8; ++i) qf[kk][i] = (short)f2bf(v[i] * SCALE);
  }

  f32x4 acc[4] = {};            // O accumulator: row q = 4g+r, col d = 16*nt+col
  float m_[4], l_[4];
  for (int r = 0; r < 4; ++r) { m_[r] = -INFINITY; l_[r] = 0.0f; }

  const int ntiles = qt + 1;    // causal: only tiles with kv <= q_max
  for (int t = 0; t < ntiles; ++t) {
    __syncthreads();            // previous tile's LDS reads complete

    // ---- stage K [64][64] fp32->bf16, row strips (coalesced) ----
    {
      const int kvr = tid >> 2;            // 0..63
      const int c0  = (tid & 3) << 4;      // 0,16,32,48
      const float* src = Kh + ((size_t)(t * KVB + kvr)) * D_ + c0;
      for (int jj = 0; jj < 2; ++jj) {
        float4 x = *(const float4*)(src + jj * 8);
        float4 y = *(const float4*)(src + jj * 8 + 4);
        u16x8 w;
        w[0] = f2bf(x.x); w[1] = f2bf(x.y); w[2] = f2bf(x.z); w[3] = f2bf(x.w);
        w[4] = f2bf(y.x); w[5] = f2bf(y.y); w[6] = f2bf(y.z); w[7] = f2bf(y.w);
        const int ch = (c0 >> 3) + jj;     // 0..7
        *(u16x8*)&Kl[kvr][(ch ^ (kvr & 7)) << 3] = w;
      }
    }
    // ---- stage V transposed: column strips (coalesced loads, b128 writes) ----
    {
      const int c  = tid & 63;             // d index
      const int r0 = (tid >> 6) << 4;      // kv 16-row strip
      const float* src = Vh + ((size_t)(t * KVB + r0)) * D_ + c;
      for (int jj = 0; jj < 2; ++jj) {
        u16x8 w;
        for (int i = 0; i < 8; ++i) w[i] = f2bf(src[(size_t)(jj * 8 + i) * D_]);
        const int ch = (r0 >> 3) + jj;     // 0..7
        *(u16x8*)&Vt[c][(ch ^ (c & 7)) << 3] = w;
      }
    }
    __syncthreads();

    // ---- S = Q K^T (scaled): s[nt] rows q=4g+r, cols kv=16nt+col ----
    f32x4 s[4] = {};
    for (int nt = 0; nt < 4; ++nt) {
      const int n = nt * 16 + col;         // kv row in Kl
      for (int kk = 0; kk < 2; ++kk) {
        const bf16x8 kf = *(const bf16x8*)&Kl[n][((((kk << 2) | g)) ^ (n & 7)) << 3];
        s[nt] = __builtin_amdgcn_mfma_f32_16x16x32_bf16(qf[kk], kf, s[nt], 0, 0, 0);
      }
    }

    // ---- causal mask on the diagonal tile ----
    if (t == qt) {
      for (int nt = 0; nt < 4; ++nt)
        for (int r = 0; r < 4; ++r)
          if (nt * 16 + col > wave * 16 + g * 4 + r) s[nt][r] = -INFINITY;
    }

    // ---- online softmax (per q row; rows live on 16-lane groups) ----
    float fac[4];
    for (int r = 0; r < 4; ++r) {
      float rm = fmaxf(fmaxf(s[0][r], s[1][r]), fmaxf(s[2][r], s[3][r]));
      for (int off = 1; off < 16; off <<= 1) rm = fmaxf(rm, __shfl_xor(rm, off));
      const float mn = fmaxf(m_[r], rm);
      fac[r] = exp2f(m_[r] - mn);
      float rs = 0.0f;
      for (int nt = 0; nt < 4; ++nt) {
        const float p = exp2f(s[nt][r] - mn);
        s[nt][r] = p;
        rs += p;
      }
      for (int off = 1; off < 16; off <<= 1) rs += __shfl_xor(rs, off);
      l_[r] = l_[r] * fac[r] + rs;
      m_[r] = mn;
    }
    for (int nt = 0; nt < 4; ++nt)
      for (int r = 0; r < 4; ++r) acc[nt][r] *= fac[r];

    // ---- P -> LDS (bf16), then read back as A fragments ----
    for (int nt = 0; nt < 4; ++nt)
      for (int r = 0; r < 4; ++r)
        Pl[wave][g * 4 + r][nt * 16 + col] = f2bf(s[nt][r]);

    // ---- O += P V : A = P[q][kv], B = V[kv][d] via Vt ----
    for (int kk = 0; kk < 2; ++kk) {
      const bf16x8 pf = *(const bf16x8*)&Pl[wave][col][((kk << 2) | g) << 3];
      for (int nt = 0; nt < 4; ++nt) {
        const int n = nt * 16 + col;       // d row in Vt
        const bf16x8 vf = *(const bf16x8*)&Vt[n][((((kk << 2) | g)) ^ (n & 7)) << 3];
        acc[nt] = __builtin_amdgcn_mfma_f32_16x16x32_bf16(pf, vf, acc[nt], 0, 0, 0);
      }
    }
  }

  // ---- epilogue: O = acc / l ----
  for (int r = 0; r < 4; ++r) {
    const float inv = 1.0f / l_[r];
    const int q = qt * QBLK + wave * 16 + g * 4 + r;
    float* dst = Oh + (size_t)q * D_;
    for (int nt = 0; nt < 4; ++nt) dst[nt * 16 + col] = acc[nt][r] * inv;
  }
}

extern "C" void kernel_launch(void* const* d_in, const int* in_sizes, int n_in,
                              void* d_out, int out_size, void* d_ws, size_t ws_size,
                              hipStream_t stream) {
  const float* Q = (const float*)d_in[0];
  const float* K = (const float*)d_in[1];
  const float* V = (const float*)d_in[2];
  float* O = (float*)d_out;
  dim3 grid(B_ * H_, S_ / QBLK);  // x = batch*head (fast), y = q tile
  attn_fwd<<<grid, 256, 0, stream>>>(Q, K, V, O);
}

// Round 3
// 69.063 us; speedup vs baseline: 1.4666x; 1.4666x over previous
//
#include <hip/hip_runtime.h>
#include <hip/hip_bf16.h>

#define B_ 2
#define H_ 16
#define S_ 2048
#define D_ 64

typedef __attribute__((ext_vector_type(8))) short bf16x8;
typedef __attribute__((ext_vector_type(8))) unsigned short u16x8;
typedef __attribute__((ext_vector_type(4))) unsigned short u16x4;
typedef __attribute__((ext_vector_type(4))) float f32x4;
typedef unsigned short ushort_t;

#define SCALE 0.18033688011112042f  // (1/sqrt(64)) * log2(e)

__device__ __forceinline__ unsigned short f2bf(float x) {
  unsigned int u = __builtin_bit_cast(unsigned int, x);
  unsigned int r = (u + 0x7FFFu + ((u >> 16) & 1u)) >> 16;
  return (unsigned short)r;
}

#define GLL16(gp, lp)                                                          \
  __builtin_amdgcn_global_load_lds(                                            \
      (const __attribute__((address_space(1))) unsigned int*)(gp),             \
      (__attribute__((address_space(3))) unsigned int*)(lp), 16, 0, 0)

// ---------------- prepass: fp32 -> bf16, swizzle baked into global layout ---
// K tile layout (per bh,t; 4096 ushorts): addr e: kv=e>>6, pos=(e>>3)&7, i=e&7
//   content = K[t*64+kv][ (pos^(kv&7))*8 + i ]
// Vt tile: d=e>>6, pos=(e>>3)&7 -> content = V[t*64 + (pos^(d&7))*8 + i][d]
__global__ void prepack(const float* __restrict__ Qf, const float* __restrict__ Kf,
                        const float* __restrict__ Vf, ushort_t* __restrict__ Qb,
                        ushort_t* __restrict__ Kg, ushort_t* __restrict__ Vtg) {
  const int blk = blockIdx.x;  // 0..1023
  const int tid = threadIdx.x;
  // Q: scaled elementwise convert (flat)
  {
    size_t base = (size_t)blk * 4096 + (size_t)tid * 16;
    const float* s = Qf + base;
    ushort_t* d = Qb + base;
    for (int h = 0; h < 2; ++h) {
      float4 a = *(const float4*)(s + h * 8);
      float4 b = *(const float4*)(s + h * 8 + 4);
      u16x8 w;
      w[0] = f2bf(a.x * SCALE); w[1] = f2bf(a.y * SCALE);
      w[2] = f2bf(a.z * SCALE); w[3] = f2bf(a.w * SCALE);
      w[4] = f2bf(b.x * SCALE); w[5] = f2bf(b.y * SCALE);
      w[6] = f2bf(b.z * SCALE); w[7] = f2bf(b.w * SCALE);
      *(u16x8*)(d + h * 8) = w;
    }
  }
  const int bh = blk >> 5, t = blk & 31;
  const float* srcK = Kf + ((size_t)bh * S_ + (size_t)t * 64) * D_;
  const float* srcV = Vf + ((size_t)bh * S_ + (size_t)t * 64) * D_;
  ushort_t* dK = Kg + (size_t)blk * 4096;
  ushort_t* dV = Vtg + (size_t)blk * 4096;
  for (int is = 0; is < 2; ++is) {
    const int e = is * 2048 + tid * 8;
    {  // K
      const int kv = e >> 6, pos = (e >> 3) & 7, ch = pos ^ (kv & 7);
      const float* sp = srcK + kv * 64 + ch * 8;
      float4 a = *(const float4*)sp;
      float4 b = *(const float4*)(sp + 4);
      u16x8 w;
      w[0] = f2bf(a.x); w[1] = f2bf(a.y); w[2] = f2bf(a.z); w[3] = f2bf(a.w);
      w[4] = f2bf(b.x); w[5] = f2bf(b.y); w[6] = f2bf(b.z); w[7] = f2bf(b.w);
      *(u16x8*)(dK + e) = w;
    }
    {  // V transposed
      const int d0 = e >> 6, pos = (e >> 3) & 7, ch = pos ^ (d0 & 7);
      u16x8 w;
      for (int i = 0; i < 8; ++i) w[i] = f2bf(srcV[(size_t)(ch * 8 + i) * 64 + d0]);
      *(u16x8*)(dV + e) = w;
    }
  }
}

// ---------------- hot kernel: swapped-QK^T flash attention, dual-stream -----
template <int PRE>
__launch_bounds__(256, 2)
__global__ void attn2(const float* __restrict__ Qf, const float* __restrict__ Kf,
                      const float* __restrict__ Vf, const ushort_t* __restrict__ Qb,
                      const ushort_t* __restrict__ Kg, const ushort_t* __restrict__ Vtg,
                      float* __restrict__ O) {
  const int bh = blockIdx.x;        // 0..31
  const int pr = blockIdx.y;        // 0..15
  const int qLo = pr, qHi = 31 - pr;
  const int tid = threadIdx.x;
  const int wave = tid >> 6, lane = tid & 63;
  const int col = lane & 15, g = lane >> 4;

  __shared__ __align__(16) ushort_t Kl[2][64][64];
  __shared__ __align__(16) ushort_t Vt[2][64][64];
  __shared__ __align__(16) ushort_t Pl[4][16][72];

  float* Oh = O + (size_t)bh * S_ * D_;

  // ---- Q fragments: lane holds Q[qbase + col][32kk + 8g + i] ----
  bf16x8 qfL[2], qfH[2];
  if (PRE) {
    const ushort_t* qb = Qb + (size_t)bh * S_ * D_;
    for (int kk = 0; kk < 2; ++kk) {
      qfL[kk] = *(const bf16x8*)&qb[((size_t)(qLo * 64 + wave * 16 + col)) * 64 + kk * 32 + g * 8];
      qfH[kk] = *(const bf16x8*)&qb[((size_t)(qHi * 64 + wave * 16 + col)) * 64 + kk * 32 + g * 8];
    }
  } else {
    const float* Qh = Qf + (size_t)bh * S_ * D_;
    for (int st = 0; st < 2; ++st) {
      const int qrow = (st ? qHi : qLo) * 64 + wave * 16 + col;
      for (int kk = 0; kk < 2; ++kk) {
        const float* p = Qh + (size_t)qrow * 64 + kk * 32 + g * 8;
        float4 a = *(const float4*)p;
        float4 b = *(const float4*)(p + 4);
        float v[8] = {a.x, a.y, a.z, a.w, b.x, b.y, b.z, b.w};
        bf16x8 w;
        for (int i = 0; i < 8; ++i) w[i] = (short)f2bf(v[i] * SCALE);
        if (st) qfH[kk] = w; else qfL[kk] = w;
      }
    }
  }

  f32x4 accL[4] = {}, accH[4] = {};
  float mL = -INFINITY, lL = 0.0f, mH = -INFINITY, lH = 0.0f;

  auto STAGE = [&](int t, int b) {
    if (PRE) {
      const ushort_t* kg = Kg + ((size_t)(bh * 32 + t)) * 4096;
      const ushort_t* vg = Vtg + ((size_t)(bh * 32 + t)) * 4096;
      GLL16(kg + tid * 8,        &Kl[b][0][0] + tid * 8);
      GLL16(kg + 2048 + tid * 8, &Kl[b][0][0] + 2048 + tid * 8);
      GLL16(vg + tid * 8,        &Vt[b][0][0] + tid * 8);
      GLL16(vg + 2048 + tid * 8, &Vt[b][0][0] + 2048 + tid * 8);
    } else {
      const float* Kh = Kf + (size_t)bh * S_ * D_;
      const float* Vh = Vf + (size_t)bh * S_ * D_;
      {  // K rows, coalesced
        const int kvr = tid >> 2;
        const int c0 = (tid & 3) << 4;
        const float* src = Kh + ((size_t)(t * 64 + kvr)) * 64 + c0;
        for (int jj = 0; jj < 2; ++jj) {
          float4 x = *(const float4*)(src + jj * 8);
          float4 y = *(const float4*)(src + jj * 8 + 4);
          u16x8 w;
          w[0] = f2bf(x.x); w[1] = f2bf(x.y); w[2] = f2bf(x.z); w[3] = f2bf(x.w);
          w[4] = f2bf(y.x); w[5] = f2bf(y.y); w[6] = f2bf(y.z); w[7] = f2bf(y.w);
          const int ch = (c0 >> 3) + jj;
          *(u16x8*)&Kl[b][kvr][(ch ^ (kvr & 7)) << 3] = w;
        }
      }
      {  // V column strips -> transposed
        const int c = tid & 63;
        const int r0 = (tid >> 6) << 4;
        const float* src = Vh + ((size_t)(t * 64 + r0)) * 64 + c;
        for (int jj = 0; jj < 2; ++jj) {
          u16x8 w;
          for (int i = 0; i < 8; ++i) w[i] = f2bf(src[(size_t)(jj * 8 + i) * 64]);
          const int ch = (r0 >> 3) + jj;
          *(u16x8*)&Vt[b][c][(ch ^ (c & 7)) << 3] = w;
        }
      }
    }
  };

  auto COMPUTE = [&](const bf16x8 (&qf)[2], f32x4 (&acc)[4], float& m_, float& l_,
                     bool diag, int b) {
    // S^T = K·Q^T : lane holds S^T[kv = nt*16+4g+r][q = qbase + wave*16 + col]
    f32x4 s[4] = {{0,0,0,0},{0,0,0,0},{0,0,0,0},{0,0,0,0}};
    for (int nt = 0; nt < 4; ++nt) {
      const int n = nt * 16 + col;
      for (int kk = 0; kk < 2; ++kk) {
        const bf16x8 kf = *(const bf16x8*)&Kl[b][n][(((kk << 2) | g) ^ (n & 7)) << 3];
        s[nt] = __builtin_amdgcn_mfma_f32_16x16x32_bf16(kf, qf[kk], s[nt], 0, 0, 0);
      }
    }
    if (diag) {
      for (int nt = 0; nt < 4; ++nt)
        for (int r = 0; r < 4; ++r)
          if (nt * 16 + 4 * g + r > wave * 16 + col) s[nt][r] = -INFINITY;
    }
    // softmax: q-row is spread over the 4 g-lanes (same col) -> in-lane 16-max
    // then cross-g combine via shfl_xor(16), shfl_xor(32).
    float pm = fmaxf(fmaxf(fmaxf(s[0][0], s[0][1]), fmaxf(s[0][2], s[0][3])),
                     fmaxf(fmaxf(s[1][0], s[1][1]), fmaxf(s[1][2], s[1][3])));
    pm = fmaxf(pm, fmaxf(fmaxf(fmaxf(s[2][0], s[2][1]), fmaxf(s[2][2], s[2][3])),
                         fmaxf(fmaxf(s[3][0], s[3][1]), fmaxf(s[3][2], s[3][3]))));
    pm = fmaxf(pm, __shfl_xor(pm, 16));
    pm = fmaxf(pm, __shfl_xor(pm, 32));
    const float mn = fmaxf(m_, pm);
    const float fac = exp2f(m_ - mn);
    float sum = 0.0f;
    for (int nt = 0; nt < 4; ++nt)
      for (int r = 0; r < 4; ++r) {
        const float p = exp2f(s[nt][r] - mn);
        s[nt][r] = p;
        sum += p;
      }
    sum += __shfl_xor(sum, 16);
    sum += __shfl_xor(sum, 32);
    l_ = l_ * fac + sum;
    m_ = mn;
    for (int nt = 0; nt < 4; ++nt) acc[nt] *= fac;
    // P -> LDS (per-wave buffer): Pl[wave][q=col][kv]
    for (int nt = 0; nt < 4; ++nt) {
      u16x4 w;
      w[0] = f2bf(s[nt][0]); w[1] = f2bf(s[nt][1]);
      w[2] = f2bf(s[nt][2]); w[3] = f2bf(s[nt][3]);
      *(u16x4*)&Pl[wave][col][nt * 16 + 4 * g] = w;
    }
    // O^T += V^T · P^T
    for (int kk = 0; kk < 2; ++kk) {
      const bf16x8 pf = *(const bf16x8*)&Pl[wave][col][kk * 32 + 8 * g];
      for (int nt = 0; nt < 4; ++nt) {
        const int n = nt * 16 + col;
        const bf16x8 vf = *(const bf16x8*)&Vt[b][n][(((kk << 2) | g) ^ (n & 7)) << 3];
        acc[nt] = __builtin_amdgcn_mfma_f32_16x16x32_bf16(vf, pf, acc[nt], 0, 0, 0);
      }
    }
  };

  int cur = 0;
  STAGE(0, 0);
  __syncthreads();
  for (int t = 0; t <= qHi; ++t) {
    if (t < qHi) STAGE(t + 1, cur ^ 1);
    COMPUTE(qfH, accH, mH, lH, t == qHi, cur);
    if (t <= qLo) COMPUTE(qfL, accL, mL, lL, t == qLo, cur);
    __syncthreads();
    cur ^= 1;
  }

  // ---- epilogue: lane holds O^T[d=nt*16+4g+r][q=qbase+wave*16+col] ----
  for (int st = 0; st < 2; ++st) {
    const int qrow = (st ? qHi : qLo) * 64 + wave * 16 + col;
    const float inv = 1.0f / (st ? lH : lL);
    float* dst = Oh + (size_t)qrow * 64;
    for (int nt = 0; nt < 4; ++nt) {
      f32x4 v = (st ? accH[nt] : accL[nt]);
      v *= inv;
      *(f32x4*)(dst + nt * 16 + 4 * g) = v;
    }
  }
}

extern "C" void kernel_launch(void* const* d_in, const int* in_sizes, int n_in,
                              void* d_out, int out_size, void* d_ws, size_t ws_size,
                              hipStream_t stream) {
  const float* Q = (const float*)d_in[0];
  const float* K = (const float*)d_in[1];
  const float* V = (const float*)d_in[2];
  float* O = (float*)d_out;
  const size_t NE = (size_t)B_ * H_ * S_ * D_;  // 4194304
  if (ws_size >= 3 * NE * sizeof(ushort_t)) {
    ushort_t* qb = (ushort_t*)d_ws;
    prepack<<<1024, 256, 0, stream>>>(Q, K, V, qb, qb + NE, qb + 2 * NE);
    attn2<1><<<dim3(32, 16), 256, 0, stream>>>(Q, K, V, qb, qb + NE, qb + 2 * NE, O);
  } else {
    attn2<0><<<dim3(32, 16), 256, 0, stream>>>(Q, K, V, nullptr, nullptr, nullptr, O);
  }
}

// Round 4
// 61.052 us; speedup vs baseline: 1.6591x; 1.1312x over previous
//
#include <hip/hip_runtime.h>
#include <hip/hip_bf16.h>

#define B_ 2
#define H_ 16
#define S_ 2048
#define D_ 64

typedef __attribute__((ext_vector_type(8))) short bf16x8;
typedef __attribute__((ext_vector_type(8))) unsigned short u16x8;
typedef __attribute__((ext_vector_type(2))) unsigned int u32x2;
typedef __attribute__((ext_vector_type(4))) float f32x4;
typedef unsigned short ushort_t;

#define SCALE 0.18033688011112042f  // (1/sqrt(64)) * log2(e)

__device__ __forceinline__ unsigned short f2bf(float x) {
  unsigned int u = __builtin_bit_cast(unsigned int, x);
  unsigned int r = (u + 0x7FFFu + ((u >> 16) & 1u)) >> 16;
  return (unsigned short)r;
}

// packed f32 pair -> bf16 pair (RNE), lo in [15:0], hi in [31:16]
__device__ __forceinline__ unsigned int cvt_pk_bf16(float lo, float hi) {
  unsigned int r;
  asm("v_cvt_pk_bf16_f32 %0, %1, %2" : "=v"(r) : "v"(lo), "v"(hi));
  return r;
}

#define GLL16(gp, lp)                                                          \
  __builtin_amdgcn_global_load_lds(                                            \
      (const __attribute__((address_space(1))) unsigned int*)(gp),             \
      (__attribute__((address_space(3))) unsigned int*)(lp), 16, 0, 0)

// ---------------- prepass: K/V fp32 -> bf16, swizzle baked into layout ------
// K tile (per bh,t; 4096 ushorts): addr e: kv=e>>6, pos=(e>>3)&7, i=e&7
//   content = K[t*64+kv][ (pos^(kv&7))*8 + i ]
// Vt tile: d=e>>6 -> content = V[t*64 + (pos^(d&7))*8 + i][d]
__global__ void prepack(const float* __restrict__ Kf, const float* __restrict__ Vf,
                        ushort_t* __restrict__ Kg, ushort_t* __restrict__ Vtg) {
  const int blk = blockIdx.x;  // 0..1023  (bh*32 + t)
  const int tid = threadIdx.x;
  const int bh = blk >> 5, t = blk & 31;
  const float* srcK = Kf + ((size_t)bh * S_ + (size_t)t * 64) * D_;
  const float* srcV = Vf + ((size_t)bh * S_ + (size_t)t * 64) * D_;
  ushort_t* dK = Kg + (size_t)blk * 4096;
  ushort_t* dV = Vtg + (size_t)blk * 4096;
  for (int is = 0; is < 2; ++is) {
    const int e = is * 2048 + tid * 8;
    {  // K
      const int kv = e >> 6, pos = (e >> 3) & 7, ch = pos ^ (kv & 7);
      const float* sp = srcK + kv * 64 + ch * 8;
      float4 a = *(const float4*)sp;
      float4 b = *(const float4*)(sp + 4);
      u16x8 w;
      w[0] = f2bf(a.x); w[1] = f2bf(a.y); w[2] = f2bf(a.z); w[3] = f2bf(a.w);
      w[4] = f2bf(b.x); w[5] = f2bf(b.y); w[6] = f2bf(b.z); w[7] = f2bf(b.w);
      *(u16x8*)(dK + e) = w;
    }
    {  // V transposed
      const int d0 = e >> 6, pos = (e >> 3) & 7, ch = pos ^ (d0 & 7);
      u16x8 w;
      for (int i = 0; i < 8; ++i) w[i] = f2bf(srcV[(size_t)(ch * 8 + i) * 64 + d0]);
      *(u16x8*)(dV + e) = w;
    }
  }
}

// ---------------- hot kernel: swapped-QK^T flash attention ------------------
template <int PRE>
__launch_bounds__(256, 3)
__global__ void attn3(const float* __restrict__ Qf, const float* __restrict__ Kf,
                      const float* __restrict__ Vf, const ushort_t* __restrict__ Kg,
                      const ushort_t* __restrict__ Vtg, float* __restrict__ O) {
  const int bh = blockIdx.x;          // 0..31
  const int qt = 31 - blockIdx.y;     // LPT: longest blocks dispatched first
  const int tid = threadIdx.x;
  const int wave = tid >> 6, lane = tid & 63;
  const int col = lane & 15, g = lane >> 4;

  __shared__ __align__(16) ushort_t Kl[2][64][64];
  __shared__ __align__(16) ushort_t Vt[2][64][64];
  __shared__ __align__(16) ushort_t Pl[4][16][72];

  float* Oh = O + (size_t)bh * S_ * D_;

  // ---- Q fragment from fp32 (one-time): lane holds Q[qrow][32kk+8g+i] ----
  const int qrow = qt * 64 + wave * 16 + col;
  bf16x8 qf[2];
  {
    const float* Qh = Qf + (size_t)bh * S_ * D_;
    for (int kk = 0; kk < 2; ++kk) {
      const float* p = Qh + (size_t)qrow * 64 + kk * 32 + g * 8;
      float4 a = *(const float4*)p;
      float4 b = *(const float4*)(p + 4);
      float v[8] = {a.x, a.y, a.z, a.w, b.x, b.y, b.z, b.w};
      bf16x8 w;
      for (int i = 0; i < 8; ++i) w[i] = (short)f2bf(v[i] * SCALE);
      qf[kk] = w;
    }
  }

  f32x4 acc[4] = {};
  float m_ = -INFINITY, l_ = 0.0f;

  // per-lane constant LDS chunk offsets (XOR swizzle is nt-independent)
  const int ch0 = (g ^ (col & 7)) << 3;
  const int ch1 = ((4 | g) ^ (col & 7)) << 3;

  auto STAGE = [&](int t, int b) {
    if (PRE) {
      const ushort_t* kg = Kg + ((size_t)(bh * 32 + t)) * 4096;
      const ushort_t* vg = Vtg + ((size_t)(bh * 32 + t)) * 4096;
      GLL16(kg + tid * 8,        &Kl[b][0][0] + tid * 8);
      GLL16(kg + 2048 + tid * 8, &Kl[b][0][0] + 2048 + tid * 8);
      GLL16(vg + tid * 8,        &Vt[b][0][0] + tid * 8);
      GLL16(vg + 2048 + tid * 8, &Vt[b][0][0] + 2048 + tid * 8);
    } else {
      const float* Kh = Kf + (size_t)bh * S_ * D_;
      const float* Vh = Vf + (size_t)bh * S_ * D_;
      {  // K rows, coalesced
        const int kvr = tid >> 2;
        const int c0 = (tid & 3) << 4;
        const float* src = Kh + ((size_t)(t * 64 + kvr)) * 64 + c0;
        for (int jj = 0; jj < 2; ++jj) {
          float4 x = *(const float4*)(src + jj * 8);
          float4 y = *(const float4*)(src + jj * 8 + 4);
          u16x8 w;
          w[0] = f2bf(x.x); w[1] = f2bf(x.y); w[2] = f2bf(x.z); w[3] = f2bf(x.w);
          w[4] = f2bf(y.x); w[5] = f2bf(y.y); w[6] = f2bf(y.z); w[7] = f2bf(y.w);
          const int ch = (c0 >> 3) + jj;
          *(u16x8*)&Kl[b][kvr][(ch ^ (kvr & 7)) << 3] = w;
        }
      }
      {  // V column strips -> transposed
        const int c = tid & 63;
        const int r0 = (tid >> 6) << 4;
        const float* src = Vh + ((size_t)(t * 64 + r0)) * 64 + c;
        for (int jj = 0; jj < 2; ++jj) {
          u16x8 w;
          for (int i = 0; i < 8; ++i) w[i] = f2bf(src[(size_t)(jj * 8 + i) * 64]);
          const int ch = (r0 >> 3) + jj;
          *(u16x8*)&Vt[b][c][(ch ^ (c & 7)) << 3] = w;
        }
      }
    }
  };

  auto COMPUTE = [&](int b, bool diag) {
    // S^T = K·Q^T : lane holds S^T[kv = nt*16+4g+r][q = qrow]
    f32x4 s[4] = {{0,0,0,0},{0,0,0,0},{0,0,0,0},{0,0,0,0}};
    __builtin_amdgcn_s_setprio(1);
    for (int nt = 0; nt < 4; ++nt) {
      const ushort_t* row = &Kl[b][nt * 16 + col][0];
      const bf16x8 kf0 = *(const bf16x8*)(row + ch0);
      const bf16x8 kf1 = *(const bf16x8*)(row + ch1);
      s[nt] = __builtin_amdgcn_mfma_f32_16x16x32_bf16(kf0, qf[0], s[nt], 0, 0, 0);
      s[nt] = __builtin_amdgcn_mfma_f32_16x16x32_bf16(kf1, qf[1], s[nt], 0, 0, 0);
    }
    __builtin_amdgcn_s_setprio(0);
    if (diag) {
      for (int nt = 0; nt < 4; ++nt)
        for (int r = 0; r < 4; ++r)
          if (nt * 16 + 4 * g + r > wave * 16 + col) s[nt][r] = -INFINITY;
    }
    // row max: 16 in-lane values, then combine the 4 g-lanes of this q-row
    float pm = fmaxf(fmaxf(fmaxf(s[0][0], s[0][1]), fmaxf(s[0][2], s[0][3])),
                     fmaxf(fmaxf(s[1][0], s[1][1]), fmaxf(s[1][2], s[1][3])));
    pm = fmaxf(pm, fmaxf(fmaxf(fmaxf(s[2][0], s[2][1]), fmaxf(s[2][2], s[2][3])),
                         fmaxf(fmaxf(s[3][0], s[3][1]), fmaxf(s[3][2], s[3][3]))));
    pm = fmaxf(pm, __shfl_xor(pm, 16));
    pm = fmaxf(pm, __shfl_xor(pm, 32));
    float fac = 1.0f;
    if (!__all(pm - m_ <= 8.0f)) {  // defer-max (T13): rescale only when needed
      const float mn = fmaxf(m_, pm);
      fac = exp2f(m_ - mn);
      m_ = mn;
      for (int nt = 0; nt < 4; ++nt) acc[nt] *= fac;
    }
    float sum = 0.0f;
    for (int nt = 0; nt < 4; ++nt)
      for (int r = 0; r < 4; ++r) {
        const float p = exp2f(s[nt][r] - m_);
        s[nt][r] = p;
        sum += p;
      }
    sum += __shfl_xor(sum, 16);
    sum += __shfl_xor(sum, 32);
    l_ = l_ * fac + sum;
    // P -> LDS (per-wave): Pl[wave][q=col][kv], packed bf16 via cvt_pk
    for (int nt = 0; nt < 4; ++nt) {
      u32x2 w;
      w[0] = cvt_pk_bf16(s[nt][0], s[nt][1]);
      w[1] = cvt_pk_bf16(s[nt][2], s[nt][3]);
      *(u32x2*)&Pl[wave][col][nt * 16 + 4 * g] = w;
    }
    // O^T += V^T · P^T
    const bf16x8 pf0 = *(const bf16x8*)&Pl[wave][col][8 * g];
    const bf16x8 pf1 = *(const bf16x8*)&Pl[wave][col][32 + 8 * g];
    __builtin_amdgcn_s_setprio(1);
    for (int nt = 0; nt < 4; ++nt) {
      const ushort_t* row = &Vt[b][nt * 16 + col][0];
      const bf16x8 vf0 = *(const bf16x8*)(row + ch0);
      const bf16x8 vf1 = *(const bf16x8*)(row + ch1);
      acc[nt] = __builtin_amdgcn_mfma_f32_16x16x32_bf16(vf0, pf0, acc[nt], 0, 0, 0);
      acc[nt] = __builtin_amdgcn_mfma_f32_16x16x32_bf16(vf1, pf1, acc[nt], 0, 0, 0);
    }
    __builtin_amdgcn_s_setprio(0);
  };

  int cur = 0;
  STAGE(0, 0);
  __syncthreads();
  for (int t = 0; t <= qt; ++t) {
    if (t < qt) STAGE(t + 1, cur ^ 1);
    COMPUTE(cur, t == qt);
    __syncthreads();
    cur ^= 1;
  }

  // ---- epilogue: lane holds O^T[d=nt*16+4g+r][qrow] ----
  const float inv = 1.0f / l_;
  float* dst = Oh + (size_t)qrow * 64;
  for (int nt = 0; nt < 4; ++nt) {
    f32x4 v = acc[nt];
    v *= inv;
    *(f32x4*)(dst + nt * 16 + 4 * g) = v;
  }
}

extern "C" void kernel_launch(void* const* d_in, const int* in_sizes, int n_in,
                              void* d_out, int out_size, void* d_ws, size_t ws_size,
                              hipStream_t stream) {
  const float* Q = (const float*)d_in[0];
  const float* K = (const float*)d_in[1];
  const float* V = (const float*)d_in[2];
  float* O = (float*)d_out;
  const size_t NE = (size_t)B_ * H_ * S_ * D_;  // 4194304
  if (ws_size >= 2 * NE * sizeof(ushort_t)) {
    ushort_t* kg = (ushort_t*)d_ws;
    prepack<<<1024, 256, 0, stream>>>(K, V, kg, kg + NE);
    attn3<1><<<dim3(32, 32), 256, 0, stream>>>(Q, K, V, kg, kg + NE, O);
  } else {
    attn3<0><<<dim3(32, 32), 256, 0, stream>>>(Q, K, V, nullptr, nullptr, O);
  }
}